// Round 2
// baseline (1004.515 us; speedup 1.0000x reference)
//
#include <hip/hip_runtime.h>

// GCN: N=100000 nodes, E=1600000 edges, dims 128 -> 64 -> 32.
// CSR-by-destination built per launch; aggregation is gather-based (no feature atomics).
// layer1: h1 = relu(dinv * (self + sum_nbr) of g1 + b1), g1 = dinv * (x@W1)
// layer2: out =       dinv * (self + sum_nbr) of g2 + b2, g2 = dinv * (h1@W2)

#define NNODES 100000
#define NEDGES 1600000
#define IN_DIM 128
#define HID 64
#define OUTD 32

// ---- CSR build ----

__global__ void k_count(const int* __restrict__ col, int* __restrict__ cnt) {
    int e = blockIdx.x * blockDim.x + threadIdx.x;
    if (e < NEDGES) atomicAdd(&cnt[col[e]], 1);
}

// single-workgroup scan over 100k counts -> ptr (exclusive), cursor (copy), dinv
__global__ __launch_bounds__(1024) void k_scan(const int* __restrict__ cnt,
                                               int* __restrict__ ptr,
                                               int* __restrict__ cursor,
                                               float* __restrict__ dinv) {
    __shared__ int sums[1024];
    int t = threadIdx.x;
    const int CHUNK = (NNODES + 1023) / 1024;  // 98
    int lo = t * CHUNK;
    int hi = lo + CHUNK; if (hi > NNODES) hi = NNODES;
    int s = 0;
    for (int i = lo; i < hi; ++i) s += cnt[i];
    sums[t] = s;
    __syncthreads();
    // Hillis-Steele inclusive scan over 1024 partials
    for (int off = 1; off < 1024; off <<= 1) {
        int v = (t >= off) ? sums[t - off] : 0;
        __syncthreads();
        sums[t] += v;
        __syncthreads();
    }
    int running = (t == 0) ? 0 : sums[t - 1];
    for (int i = lo; i < hi; ++i) {
        int c = cnt[i];
        ptr[i] = running;
        cursor[i] = running;
        dinv[i] = rsqrtf((float)c + 1.0f);  // +1 self-loop
        running += c;
    }
    if (t == 0) ptr[NNODES] = NEDGES;
}

__global__ void k_fill(const int* __restrict__ row, const int* __restrict__ col,
                       int* __restrict__ cursor, int* __restrict__ adj) {
    int e = blockIdx.x * blockDim.x + threadIdx.x;
    if (e < NEDGES) {
        int c = col[e];
        int pos = atomicAdd(&cursor[c], 1);
        adj[pos] = row[e];
    }
}

// ---- layer kernels ----

// g1 = dinv * (x @ W1); one wave per node, lane = hidden feature j.
__global__ void k_gemm1(const float* __restrict__ x, const float* __restrict__ W1,
                        const float* __restrict__ dinv, float* __restrict__ g1) {
    int t = blockIdx.x * blockDim.x + threadIdx.x;
    int i = t >> 6;
    int j = t & 63;
    if (i >= NNODES) return;
    const float* xr = x + (size_t)i * IN_DIM;
    float s = 0.0f;
#pragma unroll 8
    for (int k = 0; k < IN_DIM; ++k) {
        s = fmaf(xr[k], W1[k * HID + j], s);  // xr[k] wave-broadcast, W1 row coalesced (32KB, L1-hot)
    }
    g1[(size_t)i * HID + j] = dinv[i] * s;
}

// h1 = relu(dinv * (g1[i] + sum_nbr g1[nbr]) + b1); one wave per node.
__global__ void k_agg1(const float* __restrict__ g1, const int* __restrict__ ptr,
                       const int* __restrict__ adj, const float* __restrict__ dinv,
                       const float* __restrict__ b1, float* __restrict__ h1) {
    int t = blockIdx.x * blockDim.x + threadIdx.x;
    int i = t >> 6;
    int j = t & 63;
    if (i >= NNODES) return;
    float s = g1[(size_t)i * HID + j];  // self loop
    int p0 = ptr[i], p1 = ptr[i + 1];
    for (int p = p0; p < p1; ++p) {
        int nbr = adj[p];               // wave-broadcast read
        s += g1[(size_t)nbr * HID + j]; // coalesced 256B gather
    }
    float v = fmaf(dinv[i], s, b1[j]);
    h1[(size_t)i * HID + j] = fmaxf(v, 0.0f);
}

// g2 = dinv * (h1 @ W2); half-wave per node, lane = out feature j2.
__global__ void k_gemm2(const float* __restrict__ h1, const float* __restrict__ W2,
                        const float* __restrict__ dinv, float* __restrict__ g2) {
    int t = blockIdx.x * blockDim.x + threadIdx.x;
    int i = t >> 5;
    int j2 = t & 31;
    if (i >= NNODES) return;
    const float* hr = h1 + (size_t)i * HID;
    float s = 0.0f;
#pragma unroll 8
    for (int j = 0; j < HID; ++j) {
        s = fmaf(hr[j], W2[j * OUTD + j2], s);  // W2 8KB, L1-hot
    }
    g2[(size_t)i * OUTD + j2] = dinv[i] * s;
}

// out = dinv * (g2[i] + sum_nbr g2[nbr]) + b2; half-wave per node.
__global__ void k_agg2(const float* __restrict__ g2, const int* __restrict__ ptr,
                       const int* __restrict__ adj, const float* __restrict__ dinv,
                       const float* __restrict__ b2, float* __restrict__ out) {
    int t = blockIdx.x * blockDim.x + threadIdx.x;
    int i = t >> 5;
    int j = t & 31;
    if (i >= NNODES) return;
    float s = g2[(size_t)i * OUTD + j];  // self loop
    int p0 = ptr[i], p1 = ptr[i + 1];
    for (int p = p0; p < p1; ++p) {
        int nbr = adj[p];
        s += g2[(size_t)nbr * OUTD + j];  // coalesced 128B gather
    }
    out[(size_t)i * OUTD + j] = fmaf(dinv[i], s, b2[j]);
}

extern "C" void kernel_launch(void* const* d_in, const int* in_sizes, int n_in,
                              void* d_out, int out_size, void* d_ws, size_t ws_size,
                              hipStream_t stream) {
    const float* x  = (const float*)d_in[0];
    const int*   ei = (const int*)d_in[1];   // [2, E]
    const float* W1 = (const float*)d_in[2];
    const float* b1 = (const float*)d_in[3];
    const float* W2 = (const float*)d_in[4];
    const float* b2 = (const float*)d_in[5];
    float* out = (float*)d_out;

    const int* row = ei;            // source
    const int* col = ei + NEDGES;   // target

    // workspace layout (all re-poisoned to 0xAA every launch)
    char* ws = (char*)d_ws;
    size_t off = 0;
    auto alloc = [&](size_t bytes) {
        void* p = ws + off;
        off = (off + bytes + 511) & ~(size_t)511;
        return p;
    };
    int*   cnt    = (int*)  alloc((size_t)NNODES * 4);
    int*   ptr    = (int*)  alloc((size_t)(NNODES + 1) * 4);
    int*   cursor = (int*)  alloc((size_t)NNODES * 4);
    float* dinv   = (float*)alloc((size_t)NNODES * 4);
    int*   adj    = (int*)  alloc((size_t)NEDGES * 4);
    float* g1     = (float*)alloc((size_t)NNODES * HID * 4);
    float* h1     = (float*)alloc((size_t)NNODES * HID * 4);
    float* g2     = g1;  // g1 dead after k_agg1

    const int B = 256;
    hipMemsetAsync(cnt, 0, (size_t)NNODES * 4, stream);
    k_count<<<(NEDGES + B - 1) / B, B, 0, stream>>>(col, cnt);
    k_scan<<<1, 1024, 0, stream>>>(cnt, ptr, cursor, dinv);
    k_fill<<<(NEDGES + B - 1) / B, B, 0, stream>>>(row, col, cursor, adj);

    {
        long long tot = (long long)NNODES * HID;
        k_gemm1<<<(int)((tot + B - 1) / B), B, 0, stream>>>(x, W1, dinv, g1);
        k_agg1 <<<(int)((tot + B - 1) / B), B, 0, stream>>>(g1, ptr, adj, dinv, b1, h1);
    }
    {
        long long tot = (long long)NNODES * OUTD;
        k_gemm2<<<(int)((tot + B - 1) / B), B, 0, stream>>>(h1, W2, dinv, g2);
        k_agg2 <<<(int)((tot + B - 1) / B), B, 0, stream>>>(g2, ptr, adj, dinv, b2, out);
    }
}

// Round 3
// 697.196 us; speedup vs baseline: 1.4408x; 1.4408x over previous
//
#include <hip/hip_runtime.h>

// GCN: N=100000 nodes, E=1600000 edges, dims 128 -> 64 -> 32.
// CSR-by-destination built per launch (parallel 3-phase scan); gather-based agg.
// layer1+2a fused: h1 = relu(dinv*(self+sum_nbr)g1 + b1); g2 = dinv*(h1@W2) in-wave
// layer2b: out = dinv*(self+sum_nbr)g2 + b2

#define NNODES 100000
#define NEDGES 1600000
#define IN_DIM 128
#define HID 64
#define OUTD 32
#define NB 98  // ceil(NNODES/1024)

// ---- CSR build ----

__global__ void k_count(const int* __restrict__ col, int* __restrict__ cnt) {
    int e = blockIdx.x * blockDim.x + threadIdx.x;
    if (e < NEDGES) atomicAdd(&cnt[col[e]], 1);
}

// phase A: per-1024-chunk sums
__global__ __launch_bounds__(256) void k_blockred(const int* __restrict__ cnt,
                                                  int* __restrict__ bsum) {
    __shared__ int s[256];
    int b = blockIdx.x, t = threadIdx.x;
    int base = b * 1024 + t * 4;
    int v = 0;
#pragma unroll
    for (int k = 0; k < 4; ++k) { int i = base + k; if (i < NNODES) v += cnt[i]; }
    s[t] = v;
    __syncthreads();
    for (int off = 128; off > 0; off >>= 1) {
        if (t < off) s[t] += s[t + off];
        __syncthreads();
    }
    if (t == 0) bsum[b] = s[0];
}

// phase B: scan the 98 block sums (1 tiny block), set ptr[NNODES]
__global__ __launch_bounds__(128) void k_scanb(const int* __restrict__ bsum,
                                               int* __restrict__ bofs,
                                               int* __restrict__ ptr) {
    __shared__ int s[128];
    int t = threadIdx.x;
    int v = (t < NB) ? bsum[t] : 0;
    s[t] = v;
    __syncthreads();
    for (int off = 1; off < 128; off <<= 1) {
        int u = (t >= off) ? s[t - off] : 0;
        __syncthreads();
        s[t] += u;
        __syncthreads();
    }
    if (t < NB) bofs[t] = s[t] - v;  // exclusive
    if (t == 0) ptr[NNODES] = NEDGES;
}

// phase C: block-local exclusive scan + block offset -> ptr/cursor/dinv
__global__ __launch_bounds__(1024) void k_scanwrite(const int* __restrict__ cnt,
                                                    const int* __restrict__ bofs,
                                                    int* __restrict__ ptr,
                                                    int* __restrict__ cursor,
                                                    float* __restrict__ dinv) {
    __shared__ int s[1024];
    int b = blockIdx.x, t = threadIdx.x;
    int i = b * 1024 + t;
    int v = (i < NNODES) ? cnt[i] : 0;
    s[t] = v;
    __syncthreads();
    for (int off = 1; off < 1024; off <<= 1) {
        int u = (t >= off) ? s[t - off] : 0;
        __syncthreads();
        s[t] += u;
        __syncthreads();
    }
    if (i < NNODES) {
        int excl = s[t] - v + bofs[b];
        ptr[i] = excl;
        cursor[i] = excl;
        dinv[i] = rsqrtf((float)v + 1.0f);  // +1 self-loop
    }
}

__global__ void k_fill(const int* __restrict__ row, const int* __restrict__ col,
                       int* __restrict__ cursor, int* __restrict__ adj) {
    int e = blockIdx.x * blockDim.x + threadIdx.x;
    if (e < NEDGES) {
        int c = col[e];
        int pos = atomicAdd(&cursor[c], 1);
        adj[pos] = row[e];
    }
}

// ---- layer kernels ----

// g1 = dinv * (x @ W1); one wave per node, lane = hidden feature j.
__global__ void k_gemm1(const float* __restrict__ x, const float* __restrict__ W1,
                        const float* __restrict__ dinv, float* __restrict__ g1) {
    int t = blockIdx.x * blockDim.x + threadIdx.x;
    int i = t >> 6;
    int j = t & 63;
    if (i >= NNODES) return;
    const float* xr = x + (size_t)i * IN_DIM;
    float s = 0.0f;
#pragma unroll 8
    for (int k = 0; k < IN_DIM; ++k) {
        s = fmaf(xr[k], W1[k * HID + j], s);  // xr[k] wave-broadcast, W1 coalesced (32KB, L1-hot)
    }
    g1[(size_t)i * HID + j] = dinv[i] * s;
}

// fused: h1 = relu(dinv*(g1[i]+sum_nbr g1)+b1)  (in regs/LDS, never to global)
//        g2 = dinv*(h1 @ W2)                    (lane-halves + shfl_xor)
// one wave per node; block = 4 waves.
__global__ __launch_bounds__(256) void k_agg1g2(const float* __restrict__ g1,
                                                const int* __restrict__ ptr,
                                                const int* __restrict__ adj,
                                                const float* __restrict__ dinv,
                                                const float* __restrict__ b1,
                                                const float* __restrict__ W2,
                                                float* __restrict__ g2) {
    __shared__ float sh[4][HID];
    int t = blockIdx.x * blockDim.x + threadIdx.x;
    int i = t >> 6;
    if (i >= NNODES) return;
    int lane = threadIdx.x & 63;
    int w = threadIdx.x >> 6;

    // aggregation (lane = hidden feature)
    float s = g1[(size_t)i * HID + lane];  // self loop
    int p0 = ptr[i], p1 = ptr[i + 1];
    for (int p = p0; p < p1; ++p) {
        int nbr = adj[p];                   // wave-broadcast
        s += g1[(size_t)nbr * HID + lane];  // coalesced 256B gather
    }
    float di = dinv[i];
    float h = fmaxf(fmaf(di, s, b1[lane]), 0.0f);
    sh[w][lane] = h;
    // wave-synchronous producer/consumer: no barrier needed (single wave)

    // matvec h1(64) @ W2(64x32): lane = (half, j2); each half sums 32 terms
    int j2 = lane & 31;
    int half = lane >> 5;
    float acc = 0.0f;
#pragma unroll
    for (int j = 0; j < 32; ++j) {
        int jj = half * 32 + j;
        acc = fmaf(sh[w][jj], W2[jj * OUTD + j2], acc);  // sh broadcast, W2 L1-hot
    }
    acc += __shfl_xor(acc, 32);
    if (half == 0) g2[(size_t)i * OUTD + j2] = di * acc;
}

// out = dinv * (g2[i] + sum_nbr g2[nbr]) + b2; half-wave per node.
__global__ void k_agg2(const float* __restrict__ g2, const int* __restrict__ ptr,
                       const int* __restrict__ adj, const float* __restrict__ dinv,
                       const float* __restrict__ b2, float* __restrict__ out) {
    int t = blockIdx.x * blockDim.x + threadIdx.x;
    int i = t >> 5;
    int j = t & 31;
    if (i >= NNODES) return;
    float s = g2[(size_t)i * OUTD + j];  // self loop
    int p0 = ptr[i], p1 = ptr[i + 1];
    for (int p = p0; p < p1; ++p) {
        int nbr = adj[p];
        s += g2[(size_t)nbr * OUTD + j];  // coalesced 128B gather
    }
    out[(size_t)i * OUTD + j] = fmaf(dinv[i], s, b2[j]);
}

extern "C" void kernel_launch(void* const* d_in, const int* in_sizes, int n_in,
                              void* d_out, int out_size, void* d_ws, size_t ws_size,
                              hipStream_t stream) {
    const float* x  = (const float*)d_in[0];
    const int*   ei = (const int*)d_in[1];   // [2, E]
    const float* W1 = (const float*)d_in[2];
    const float* b1 = (const float*)d_in[3];
    const float* W2 = (const float*)d_in[4];
    const float* b2 = (const float*)d_in[5];
    float* out = (float*)d_out;

    const int* row = ei;            // source
    const int* col = ei + NEDGES;   // target

    char* ws = (char*)d_ws;
    size_t off = 0;
    auto alloc = [&](size_t bytes) {
        void* p = ws + off;
        off = (off + bytes + 511) & ~(size_t)511;
        return p;
    };
    int*   cnt    = (int*)  alloc((size_t)NNODES * 4);
    int*   bsum   = (int*)  alloc((size_t)128 * 4);
    int*   bofs   = (int*)  alloc((size_t)128 * 4);
    int*   ptr    = (int*)  alloc((size_t)(NNODES + 1) * 4);
    int*   cursor = (int*)  alloc((size_t)NNODES * 4);
    float* dinv   = (float*)alloc((size_t)NNODES * 4);
    int*   adj    = (int*)  alloc((size_t)NEDGES * 4);
    float* g1     = (float*)alloc((size_t)NNODES * HID * 4);
    float* g2     = (float*)alloc((size_t)NNODES * OUTD * 4);

    const int B = 256;
    hipMemsetAsync(cnt, 0, (size_t)NNODES * 4, stream);
    k_count<<<(NEDGES + B - 1) / B, B, 0, stream>>>(col, cnt);
    k_blockred<<<NB, 256, 0, stream>>>(cnt, bsum);
    k_scanb<<<1, 128, 0, stream>>>(bsum, bofs, ptr);
    k_scanwrite<<<NB, 1024, 0, stream>>>(cnt, bofs, ptr, cursor, dinv);
    k_fill<<<(NEDGES + B - 1) / B, B, 0, stream>>>(row, col, cursor, adj);

    {
        long long tot = (long long)NNODES * HID;
        k_gemm1 <<<(int)((tot + B - 1) / B), B, 0, stream>>>(x, W1, dinv, g1);
        k_agg1g2<<<(int)((tot + B - 1) / B), B, 0, stream>>>(g1, ptr, adj, dinv, b1, W2, g2);
    }
    {
        long long tot = (long long)NNODES * OUTD;
        k_agg2<<<(int)((tot + B - 1) / B), B, 0, stream>>>(g2, ptr, adj, dinv, b2, out);
    }
}

// Round 4
// 496.172 us; speedup vs baseline: 2.0245x; 1.4051x over previous
//
#include <hip/hip_runtime.h>

// GCN: N=100000 nodes, E=1600000 edges, dims 128 -> 64 -> 32.
// CSR-by-destination built per launch (parallel 3-phase scan); gather-based agg.
// gemm1: register-tiled 8 nodes/wave, W1 in LDS.
// agg1+gemm2 fused; neighbor loops unrolled x4 for MLP.

#define NNODES 100000
#define NEDGES 1600000
#define IN_DIM 128
#define HID 64
#define OUTD 32
#define NB 98  // ceil(NNODES/1024)

// ---- CSR build ----

__global__ void k_count(const int* __restrict__ col, int* __restrict__ cnt) {
    int e = blockIdx.x * blockDim.x + threadIdx.x;
    if (e < NEDGES) atomicAdd(&cnt[col[e]], 1);
}

__global__ __launch_bounds__(256) void k_blockred(const int* __restrict__ cnt,
                                                  int* __restrict__ bsum) {
    __shared__ int s[256];
    int b = blockIdx.x, t = threadIdx.x;
    int base = b * 1024 + t * 4;
    int v = 0;
#pragma unroll
    for (int k = 0; k < 4; ++k) { int i = base + k; if (i < NNODES) v += cnt[i]; }
    s[t] = v;
    __syncthreads();
    for (int off = 128; off > 0; off >>= 1) {
        if (t < off) s[t] += s[t + off];
        __syncthreads();
    }
    if (t == 0) bsum[b] = s[0];
}

__global__ __launch_bounds__(128) void k_scanb(const int* __restrict__ bsum,
                                               int* __restrict__ bofs,
                                               int* __restrict__ ptr) {
    __shared__ int s[128];
    int t = threadIdx.x;
    int v = (t < NB) ? bsum[t] : 0;
    s[t] = v;
    __syncthreads();
    for (int off = 1; off < 128; off <<= 1) {
        int u = (t >= off) ? s[t - off] : 0;
        __syncthreads();
        s[t] += u;
        __syncthreads();
    }
    if (t < NB) bofs[t] = s[t] - v;  // exclusive
    if (t == 0) ptr[NNODES] = NEDGES;
}

__global__ __launch_bounds__(1024) void k_scanwrite(const int* __restrict__ cnt,
                                                    const int* __restrict__ bofs,
                                                    int* __restrict__ ptr,
                                                    int* __restrict__ cursor,
                                                    float* __restrict__ dinv) {
    __shared__ int s[1024];
    int b = blockIdx.x, t = threadIdx.x;
    int i = b * 1024 + t;
    int v = (i < NNODES) ? cnt[i] : 0;
    s[t] = v;
    __syncthreads();
    for (int off = 1; off < 1024; off <<= 1) {
        int u = (t >= off) ? s[t - off] : 0;
        __syncthreads();
        s[t] += u;
        __syncthreads();
    }
    if (i < NNODES) {
        int excl = s[t] - v + bofs[b];
        ptr[i] = excl;
        cursor[i] = excl;
        dinv[i] = rsqrtf((float)v + 1.0f);  // +1 self-loop
    }
}

__global__ void k_fill(const int* __restrict__ row, const int* __restrict__ col,
                       int* __restrict__ cursor, int* __restrict__ adj) {
    int e = blockIdx.x * blockDim.x + threadIdx.x;
    if (e < NEDGES) {
        int c = col[e];
        int pos = atomicAdd(&cursor[c], 1);
        adj[pos] = row[e];
    }
}

// ---- layer kernels ----

// g1 = dinv * (x @ W1); register-tiled: each wave computes 8 nodes, lane = j.
// W1 staged in LDS (32KB). x read as broadcast float4.
#define NT 8
__global__ __launch_bounds__(256) void k_gemm1(const float* __restrict__ x,
                                               const float* __restrict__ W1,
                                               const float* __restrict__ dinv,
                                               float* __restrict__ g1) {
    __shared__ float shW[IN_DIM * HID];  // 32 KB
    int t = threadIdx.x;
#pragma unroll
    for (int i = 0; i < (IN_DIM * HID) / 256; ++i)
        shW[t + i * 256] = W1[t + i * 256];  // coalesced
    __syncthreads();

    int wid = (blockIdx.x * blockDim.x + threadIdx.x) >> 6;
    int lane = threadIdx.x & 63;
    int base = wid * NT;
    if (base >= NNODES) return;

    const float4* xp[NT];
#pragma unroll
    for (int n = 0; n < NT; ++n)
        xp[n] = reinterpret_cast<const float4*>(x + (size_t)(base + n) * IN_DIM);

    float acc[NT];
#pragma unroll
    for (int n = 0; n < NT; ++n) acc[n] = 0.0f;

    for (int kc = 0; kc < IN_DIM / 4; ++kc) {
        float4 xv[NT];
#pragma unroll
        for (int n = 0; n < NT; ++n) xv[n] = xp[n][kc];  // broadcast 16B loads
        float w0 = shW[(kc * 4 + 0) * HID + lane];
        float w1 = shW[(kc * 4 + 1) * HID + lane];
        float w2 = shW[(kc * 4 + 2) * HID + lane];
        float w3 = shW[(kc * 4 + 3) * HID + lane];
#pragma unroll
        for (int n = 0; n < NT; ++n) {
            acc[n] = fmaf(xv[n].x, w0, acc[n]);
            acc[n] = fmaf(xv[n].y, w1, acc[n]);
            acc[n] = fmaf(xv[n].z, w2, acc[n]);
            acc[n] = fmaf(xv[n].w, w3, acc[n]);
        }
    }
#pragma unroll
    for (int n = 0; n < NT; ++n)
        g1[(size_t)(base + n) * HID + lane] = dinv[base + n] * acc[n];
}

// fused: h1 = relu(dinv*(g1[i]+sum_nbr g1)+b1) in LDS; g2 = dinv*(h1@W2).
// one wave per node; neighbor loop unrolled x4.
__global__ __launch_bounds__(256) void k_agg1g2(const float* __restrict__ g1,
                                                const int* __restrict__ ptr,
                                                const int* __restrict__ adj,
                                                const float* __restrict__ dinv,
                                                const float* __restrict__ b1,
                                                const float* __restrict__ W2,
                                                float* __restrict__ g2) {
    __shared__ float sh[4][HID];
    int t = blockIdx.x * blockDim.x + threadIdx.x;
    int i = t >> 6;
    if (i >= NNODES) return;
    int lane = threadIdx.x & 63;
    int w = threadIdx.x >> 6;

    float s = g1[(size_t)i * HID + lane];  // self loop
    int p0 = ptr[i], p1 = ptr[i + 1];
    int p = p0;
    for (; p + 4 <= p1; p += 4) {
        int n0 = adj[p], n1 = adj[p + 1], n2 = adj[p + 2], n3 = adj[p + 3];
        float v0 = g1[(size_t)n0 * HID + lane];
        float v1 = g1[(size_t)n1 * HID + lane];
        float v2 = g1[(size_t)n2 * HID + lane];
        float v3 = g1[(size_t)n3 * HID + lane];
        s += (v0 + v1) + (v2 + v3);
    }
    for (; p < p1; ++p) s += g1[(size_t)adj[p] * HID + lane];

    float di = dinv[i];
    float h = fmaxf(fmaf(di, s, b1[lane]), 0.0f);
    sh[w][lane] = h;  // wave-synchronous, no barrier needed

    // matvec h1(64) @ W2(64x32): lane = (half, j2)
    int j2 = lane & 31;
    int half = lane >> 5;
    float acc = 0.0f;
#pragma unroll
    for (int j = 0; j < 32; ++j) {
        int jj = half * 32 + j;
        acc = fmaf(sh[w][jj], W2[jj * OUTD + j2], acc);
    }
    acc += __shfl_xor(acc, 32);
    if (half == 0) g2[(size_t)i * OUTD + j2] = di * acc;
}

// out = dinv * (g2[i] + sum_nbr g2[nbr]) + b2; half-wave per node, unrolled x4.
__global__ void k_agg2(const float* __restrict__ g2, const int* __restrict__ ptr,
                       const int* __restrict__ adj, const float* __restrict__ dinv,
                       const float* __restrict__ b2, float* __restrict__ out) {
    int t = blockIdx.x * blockDim.x + threadIdx.x;
    int i = t >> 5;
    int j = t & 31;
    if (i >= NNODES) return;
    float s = g2[(size_t)i * OUTD + j];  // self loop
    int p0 = ptr[i], p1 = ptr[i + 1];
    int p = p0;
    for (; p + 4 <= p1; p += 4) {
        int n0 = adj[p], n1 = adj[p + 1], n2 = adj[p + 2], n3 = adj[p + 3];
        float v0 = g2[(size_t)n0 * OUTD + j];
        float v1 = g2[(size_t)n1 * OUTD + j];
        float v2 = g2[(size_t)n2 * OUTD + j];
        float v3 = g2[(size_t)n3 * OUTD + j];
        s += (v0 + v1) + (v2 + v3);
    }
    for (; p < p1; ++p) s += g2[(size_t)adj[p] * OUTD + j];
    out[(size_t)i * OUTD + j] = fmaf(dinv[i], s, b2[j]);
}

extern "C" void kernel_launch(void* const* d_in, const int* in_sizes, int n_in,
                              void* d_out, int out_size, void* d_ws, size_t ws_size,
                              hipStream_t stream) {
    const float* x  = (const float*)d_in[0];
    const int*   ei = (const int*)d_in[1];   // [2, E]
    const float* W1 = (const float*)d_in[2];
    const float* b1 = (const float*)d_in[3];
    const float* W2 = (const float*)d_in[4];
    const float* b2 = (const float*)d_in[5];
    float* out = (float*)d_out;

    const int* row = ei;            // source
    const int* col = ei + NEDGES;   // target

    char* ws = (char*)d_ws;
    size_t off = 0;
    auto alloc = [&](size_t bytes) {
        void* p = ws + off;
        off = (off + bytes + 511) & ~(size_t)511;
        return p;
    };
    int*   cnt    = (int*)  alloc((size_t)NNODES * 4);
    int*   bsum   = (int*)  alloc((size_t)128 * 4);
    int*   bofs   = (int*)  alloc((size_t)128 * 4);
    int*   ptr    = (int*)  alloc((size_t)(NNODES + 1) * 4);
    int*   cursor = (int*)  alloc((size_t)NNODES * 4);
    float* dinv   = (float*)alloc((size_t)NNODES * 4);
    int*   adj    = (int*)  alloc((size_t)NEDGES * 4);
    float* g1     = (float*)alloc((size_t)NNODES * HID * 4);
    float* g2     = (float*)alloc((size_t)NNODES * OUTD * 4);

    const int B = 256;
    hipMemsetAsync(cnt, 0, (size_t)NNODES * 4, stream);
    k_count<<<(NEDGES + B - 1) / B, B, 0, stream>>>(col, cnt);
    k_blockred<<<NB, 256, 0, stream>>>(cnt, bsum);
    k_scanb<<<1, 128, 0, stream>>>(bsum, bofs, ptr);
    k_scanwrite<<<NB, 1024, 0, stream>>>(cnt, bofs, ptr, cursor, dinv);
    k_fill<<<(NEDGES + B - 1) / B, B, 0, stream>>>(row, col, cursor, adj);

    {
        // 8 nodes per wave: 100000/8 = 12500 waves = 800000 threads
        long long tot = (long long)(NNODES / NT) * 64;
        k_gemm1<<<(int)((tot + B - 1) / B), B, 0, stream>>>(x, W1, dinv, g1);
    }
    {
        long long tot = (long long)NNODES * HID;
        k_agg1g2<<<(int)((tot + B - 1) / B), B, 0, stream>>>(g1, ptr, adj, dinv, b1, W2, g2);
    }
    {
        long long tot = (long long)NNODES * OUTD;
        k_agg2<<<(int)((tot + B - 1) / B), B, 0, stream>>>(g2, ptr, adj, dinv, b2, out);
    }
}

// Round 5
// 361.212 us; speedup vs baseline: 2.7810x; 1.3736x over previous
//
#include <hip/hip_runtime.h>

// GCN: N=100000 nodes, E=1600000 edges, dims 128 -> 64 -> 32.
// CSR-by-destination built per launch via bucketed counting sort (LDS-staged,
// no sub-line global scatters). Gather-based aggregation, no feature atomics.
//   pass1: partition (col,row) pairs into 782 buckets of 128 dest nodes.
//   bktscan: scan bucket sizes -> CSR bucket bases.
//   pass2: per-bucket LDS CSR build -> ptr, dinv, adj (coalesced writes only).
//   gemm1: g1 = dinv*(x@W1), register-tiled 8 nodes/wave, W1 in LDS.
//   agg1g2: h1 = relu(dinv*(self+sum_nbr)g1+b1) in LDS; g2 = dinv*(h1@W2).
//   agg2:   out = dinv*(self+sum_nbr)g2 + b2.

#define NNODES 100000
#define NEDGES 1600000
#define IN_DIM 128
#define HID 64
#define OUTD 32

#define BKT_NODES 128
#define NBUK 782                        // ceil(100000/128)
#define BKT_CAP 3584                    // slots/bucket; mean load 2048, 34 sigma headroom
#define P1_BLOCKS 256
#define P1_CHUNK (NEDGES / P1_BLOCKS)   // 6250 exactly

// ---- CSR build ----

__global__ __launch_bounds__(256) void k_pass1(const int* __restrict__ row,
                                               const int* __restrict__ col,
                                               int* __restrict__ gcur,
                                               int2* __restrict__ pairbuf) {
    __shared__ int lcnt[NBUK];
    __shared__ int lbase[NBUK];
    int t = threadIdx.x;
    int e0 = blockIdx.x * P1_CHUNK;
    int e1 = e0 + P1_CHUNK;
    for (int j = t; j < NBUK; j += 256) lcnt[j] = 0;
    __syncthreads();
    for (int e = e0 + t; e < e1; e += 256)
        atomicAdd(&lcnt[col[e] >> 7], 1);
    __syncthreads();
    for (int j = t; j < NBUK; j += 256) {
        int n = lcnt[j];
        lbase[j] = (n > 0) ? atomicAdd(&gcur[j], n) : 0;
    }
    __syncthreads();
    for (int j = t; j < NBUK; j += 256) lcnt[j] = 0;
    __syncthreads();
    for (int e = e0 + t; e < e1; e += 256) {
        int c = col[e];
        int r = row[e];
        int b = c >> 7;
        int pos = lbase[b] + atomicAdd(&lcnt[b], 1);
        if (pos < BKT_CAP) pairbuf[(size_t)b * BKT_CAP + pos] = make_int2(c, r);
    }
}

__global__ __launch_bounds__(1024) void k_bktscan(const int* __restrict__ gcur,
                                                  int* __restrict__ bktbase,
                                                  int* __restrict__ ptr) {
    __shared__ int s[1024];
    int t = threadIdx.x;
    int v = (t < NBUK) ? gcur[t] : 0;
    s[t] = v;
    __syncthreads();
    for (int off = 1; off < 1024; off <<= 1) {
        int u = (t >= off) ? s[t - off] : 0;
        __syncthreads();
        s[t] += u;
        __syncthreads();
    }
    if (t < NBUK) bktbase[t] = s[t] - v;  // exclusive
    if (t == 0) { bktbase[NBUK] = NEDGES; ptr[NNODES] = NEDGES; }
}

__global__ __launch_bounds__(256) void k_pass2(const int2* __restrict__ pairbuf,
                                               const int* __restrict__ gcur,
                                               const int* __restrict__ bktbase,
                                               int* __restrict__ ptr,
                                               float* __restrict__ dinv,
                                               int* __restrict__ adj) {
    __shared__ int ncnt[BKT_NODES];
    __shared__ int nsc[BKT_NODES];
    __shared__ int ncur[BKT_NODES];
    __shared__ int seg[BKT_CAP];
    int b = blockIdx.x;
    int t = threadIdx.x;
    int c0 = b * BKT_NODES;
    int nb = NNODES - c0; if (nb > BKT_NODES) nb = BKT_NODES;
    int size = gcur[b]; if (size > BKT_CAP) size = BKT_CAP;
    int base = bktbase[b];
    const int2* pp = pairbuf + (size_t)b * BKT_CAP;

    if (t < BKT_NODES) ncnt[t] = 0;
    __syncthreads();
    for (int k = t; k < size; k += 256)
        atomicAdd(&ncnt[pp[k].x - c0], 1);
    __syncthreads();
    int myv = (t < BKT_NODES) ? ncnt[t] : 0;
    if (t < BKT_NODES) nsc[t] = myv;
    __syncthreads();
    for (int off = 1; off < BKT_NODES; off <<= 1) {
        int u = 0;
        if (t < BKT_NODES && t >= off) u = nsc[t - off];
        __syncthreads();
        if (t < BKT_NODES) nsc[t] += u;
        __syncthreads();
    }
    if (t < BKT_NODES) {
        int excl = nsc[t] - myv;
        ncur[t] = excl;
        if (t < nb) {
            ptr[c0 + t] = base + excl;
            dinv[c0 + t] = rsqrtf((float)myv + 1.0f);  // +1 self-loop
        }
    }
    __syncthreads();
    for (int k = t; k < size; k += 256) {
        int2 pr = pp[k];
        int pos = atomicAdd(&ncur[pr.x - c0], 1);
        seg[pos] = pr.y;  // LDS scatter (cheap), global stays coalesced
    }
    __syncthreads();
    for (int k = t; k < size; k += 256) adj[base + k] = seg[k];
}

// ---- layer kernels ----

// g1 = dinv * (x @ W1); each wave computes 8 nodes, lane = hidden j; W1 in LDS.
#define NT 8
__global__ __launch_bounds__(256) void k_gemm1(const float* __restrict__ x,
                                               const float* __restrict__ W1,
                                               const float* __restrict__ dinv,
                                               float* __restrict__ g1) {
    __shared__ float shW[IN_DIM * HID];  // 32 KB
    int t = threadIdx.x;
#pragma unroll
    for (int i = 0; i < (IN_DIM * HID) / 256; ++i)
        shW[t + i * 256] = W1[t + i * 256];
    __syncthreads();

    int wid = (blockIdx.x * blockDim.x + threadIdx.x) >> 6;
    int lane = threadIdx.x & 63;
    int base = wid * NT;
    if (base >= NNODES) return;

    const float4* xp[NT];
#pragma unroll
    for (int n = 0; n < NT; ++n)
        xp[n] = reinterpret_cast<const float4*>(x + (size_t)(base + n) * IN_DIM);

    float acc[NT];
#pragma unroll
    for (int n = 0; n < NT; ++n) acc[n] = 0.0f;

    for (int kc = 0; kc < IN_DIM / 4; ++kc) {
        float4 xv[NT];
#pragma unroll
        for (int n = 0; n < NT; ++n) xv[n] = xp[n][kc];
        float w0 = shW[(kc * 4 + 0) * HID + lane];
        float w1 = shW[(kc * 4 + 1) * HID + lane];
        float w2 = shW[(kc * 4 + 2) * HID + lane];
        float w3 = shW[(kc * 4 + 3) * HID + lane];
#pragma unroll
        for (int n = 0; n < NT; ++n) {
            acc[n] = fmaf(xv[n].x, w0, acc[n]);
            acc[n] = fmaf(xv[n].y, w1, acc[n]);
            acc[n] = fmaf(xv[n].z, w2, acc[n]);
            acc[n] = fmaf(xv[n].w, w3, acc[n]);
        }
    }
#pragma unroll
    for (int n = 0; n < NT; ++n)
        g1[(size_t)(base + n) * HID + lane] = dinv[base + n] * acc[n];
}

// fused: h1 = relu(dinv*(g1[i]+sum_nbr g1)+b1) in LDS; g2 = dinv*(h1@W2).
// one wave per node; neighbor loop unrolled x8.
__global__ __launch_bounds__(256) void k_agg1g2(const float* __restrict__ g1,
                                                const int* __restrict__ ptr,
                                                const int* __restrict__ adj,
                                                const float* __restrict__ dinv,
                                                const float* __restrict__ b1,
                                                const float* __restrict__ W2,
                                                float* __restrict__ g2) {
    __shared__ float sh[4][HID];
    int t = blockIdx.x * blockDim.x + threadIdx.x;
    int i = t >> 6;
    if (i >= NNODES) return;
    int lane = threadIdx.x & 63;
    int w = threadIdx.x >> 6;

    float s = g1[(size_t)i * HID + lane];  // self loop
    int p0 = ptr[i], p1 = ptr[i + 1];
    int p = p0;
    for (; p + 8 <= p1; p += 8) {
        int n0 = adj[p],     n1 = adj[p + 1], n2 = adj[p + 2], n3 = adj[p + 3];
        int n4 = adj[p + 4], n5 = adj[p + 5], n6 = adj[p + 6], n7 = adj[p + 7];
        float v0 = g1[(size_t)n0 * HID + lane];
        float v1 = g1[(size_t)n1 * HID + lane];
        float v2 = g1[(size_t)n2 * HID + lane];
        float v3 = g1[(size_t)n3 * HID + lane];
        float v4 = g1[(size_t)n4 * HID + lane];
        float v5 = g1[(size_t)n5 * HID + lane];
        float v6 = g1[(size_t)n6 * HID + lane];
        float v7 = g1[(size_t)n7 * HID + lane];
        s += ((v0 + v1) + (v2 + v3)) + ((v4 + v5) + (v6 + v7));
    }
    for (; p < p1; ++p) s += g1[(size_t)adj[p] * HID + lane];

    float di = dinv[i];
    float h = fmaxf(fmaf(di, s, b1[lane]), 0.0f);
    sh[w][lane] = h;  // wave-synchronous, no barrier needed

    int j2 = lane & 31;
    int half = lane >> 5;
    float acc = 0.0f;
#pragma unroll
    for (int j = 0; j < 32; ++j) {
        int jj = half * 32 + j;
        acc = fmaf(sh[w][jj], W2[jj * OUTD + j2], acc);
    }
    acc += __shfl_xor(acc, 32);
    if (half == 0) g2[(size_t)i * OUTD + j2] = di * acc;
}

// out = dinv * (g2[i] + sum_nbr g2[nbr]) + b2; half-wave per node, unrolled x8.
__global__ void k_agg2(const float* __restrict__ g2, const int* __restrict__ ptr,
                       const int* __restrict__ adj, const float* __restrict__ dinv,
                       const float* __restrict__ b2, float* __restrict__ out) {
    int t = blockIdx.x * blockDim.x + threadIdx.x;
    int i = t >> 5;
    int j = t & 31;
    if (i >= NNODES) return;
    float s = g2[(size_t)i * OUTD + j];  // self loop
    int p0 = ptr[i], p1 = ptr[i + 1];
    int p = p0;
    for (; p + 8 <= p1; p += 8) {
        int n0 = adj[p],     n1 = adj[p + 1], n2 = adj[p + 2], n3 = adj[p + 3];
        int n4 = adj[p + 4], n5 = adj[p + 5], n6 = adj[p + 6], n7 = adj[p + 7];
        float v0 = g2[(size_t)n0 * OUTD + j];
        float v1 = g2[(size_t)n1 * OUTD + j];
        float v2 = g2[(size_t)n2 * OUTD + j];
        float v3 = g2[(size_t)n3 * OUTD + j];
        float v4 = g2[(size_t)n4 * OUTD + j];
        float v5 = g2[(size_t)n5 * OUTD + j];
        float v6 = g2[(size_t)n6 * OUTD + j];
        float v7 = g2[(size_t)n7 * OUTD + j];
        s += ((v0 + v1) + (v2 + v3)) + ((v4 + v5) + (v6 + v7));
    }
    for (; p < p1; ++p) s += g2[(size_t)adj[p] * OUTD + j];
    out[(size_t)i * OUTD + j] = fmaf(dinv[i], s, b2[j]);
}

extern "C" void kernel_launch(void* const* d_in, const int* in_sizes, int n_in,
                              void* d_out, int out_size, void* d_ws, size_t ws_size,
                              hipStream_t stream) {
    const float* x  = (const float*)d_in[0];
    const int*   ei = (const int*)d_in[1];   // [2, E]
    const float* W1 = (const float*)d_in[2];
    const float* b1 = (const float*)d_in[3];
    const float* W2 = (const float*)d_in[4];
    const float* b2 = (const float*)d_in[5];
    float* out = (float*)d_out;

    const int* row = ei;            // source
    const int* col = ei + NEDGES;   // target

    char* ws = (char*)d_ws;
    size_t off = 0;
    auto alloc = [&](size_t bytes) {
        void* p = ws + off;
        off = (off + bytes + 511) & ~(size_t)511;
        return p;
    };
    int*   gcur    = (int*)  alloc((size_t)NBUK * 4);
    int*   bktbase = (int*)  alloc((size_t)(NBUK + 1) * 4);
    int*   ptr     = (int*)  alloc((size_t)(NNODES + 1) * 4);
    float* dinv    = (float*)alloc((size_t)NNODES * 4);
    int*   adj     = (int*)  alloc((size_t)NEDGES * 4);
    float* g2      = (float*)alloc((size_t)NNODES * OUTD * 4);
    // pairbuf (22.4MB) and g1 (25.6MB) share one region: pairbuf dead after k_pass2,
    // g1 first written by k_gemm1 which runs after.
    size_t big = (size_t)NBUK * BKT_CAP * 8;
    size_t g1b = (size_t)NNODES * HID * 4;
    int2*  pairbuf = (int2*) alloc(big > g1b ? big : g1b);
    float* g1      = (float*)pairbuf;

    const int B = 256;
    hipMemsetAsync(gcur, 0, (size_t)NBUK * 4, stream);
    k_pass1<<<P1_BLOCKS, 256, 0, stream>>>(row, col, gcur, pairbuf);
    k_bktscan<<<1, 1024, 0, stream>>>(gcur, bktbase, ptr);
    k_pass2<<<NBUK, 256, 0, stream>>>(pairbuf, gcur, bktbase, ptr, dinv, adj);

    {
        long long tot = (long long)(NNODES / NT) * 64;
        k_gemm1<<<(int)((tot + B - 1) / B), B, 0, stream>>>(x, W1, dinv, g1);
    }
    {
        long long tot = (long long)NNODES * HID;
        k_agg1g2<<<(int)((tot + B - 1) / B), B, 0, stream>>>(g1, ptr, adj, dinv, b1, W2, g2);
    }
    {
        long long tot = (long long)NNODES * OUTD;
        k_agg2<<<(int)((tot + B - 1) / B), B, 0, stream>>>(g2, ptr, adj, dinv, b2, out);
    }
}